// Round 1
// baseline (307.127 us; speedup 1.0000x reference)
//
#include <hip/hip_runtime.h>
#include <hip/hip_bf16.h>
#include <math.h>

#define SEQ 8192
#define DIN 512
#define DH  64
#define SG  4                 // sequence splits (flash)
#define CHUNK (SEQ / SG)      // 2048 K-rows per block
#define BK  64                // K/V tile rows per iteration
#define NITER (CHUNK / BK)    // 32
#define LDP 72                // padded LDS row stride in bf16 (64 + 8)

typedef float f32x4 __attribute__((ext_vector_type(4)));
typedef short short8 __attribute__((ext_vector_type(8)));

static __device__ __forceinline__ ushort bf16_of(float v) {
  __hip_bfloat16 h = __float2bfloat16(v);
  return *reinterpret_cast<ushort*>(&h);
}
static __device__ __forceinline__ float f_of_bf16(ushort u) {
  __hip_bfloat16 h;
  *reinterpret_cast<ushort*>(&h) = u;
  return __bfloat162float(h);
}
static __device__ __forceinline__ f32x4 mfma16(short8 a, short8 b, f32x4 c) {
  return __builtin_amdgcn_mfma_f32_16x16x32_bf16(a, b, c, 0, 0, 0);
}

// ---------------------------------------------------------------------------
// Kernel 1: projections in exact fp32.  Q gets the 1/sqrt(64)=0.125 scale
// folded in, then Q,K are split into hi+lo bf16 (near-fp32 when recombined by
// 3-pass MFMA).  V is written TRANSPOSED as bf16 so the flash kernel's PV
// B-fragments are contiguous.  Block = 1 wave, 8 rows of x staged in LDS.
// ---------------------------------------------------------------------------
__global__ __launch_bounds__(64) void proj_kernel(
    const float* __restrict__ x,  const float* __restrict__ Wq,
    const float* __restrict__ Wk, const float* __restrict__ Wv,
    ushort* __restrict__ Qh, ushort* __restrict__ Ql,
    ushort* __restrict__ Kh, ushort* __restrict__ Kl,
    ushort* __restrict__ Vt) {
  __shared__ float sx[8][DIN];          // 16 KB
  const int tid = threadIdx.x;          // 0..63
  const int rb  = blockIdx.x * 8;

  // stage 8 rows of x (1024 float4 chunks / 64 threads = 16 each, coalesced)
  {
    const float4* xg  = reinterpret_cast<const float4*>(x + (size_t)rb * DIN);
    float4*       sxv = reinterpret_cast<float4*>(&sx[0][0]);
#pragma unroll
    for (int j = 0; j < 16; ++j) sxv[tid + 64 * j] = xg[tid + 64 * j];
  }
  __syncthreads();

  const int c = tid;  // output column 0..63, one per lane, for all 3 matrices
  float aq[8], ak[8], av[8];
#pragma unroll
  for (int r = 0; r < 8; ++r) { aq[r] = 0.f; ak[r] = 0.f; av[r] = 0.f; }

  for (int k = 0; k < DIN; k += 4) {
    float wq0 = Wq[(k + 0) * DH + c], wq1 = Wq[(k + 1) * DH + c];
    float wq2 = Wq[(k + 2) * DH + c], wq3 = Wq[(k + 3) * DH + c];
    float wk0 = Wk[(k + 0) * DH + c], wk1 = Wk[(k + 1) * DH + c];
    float wk2 = Wk[(k + 2) * DH + c], wk3 = Wk[(k + 3) * DH + c];
    float wv0 = Wv[(k + 0) * DH + c], wv1 = Wv[(k + 1) * DH + c];
    float wv2 = Wv[(k + 2) * DH + c], wv3 = Wv[(k + 3) * DH + c];
#pragma unroll
    for (int r = 0; r < 8; ++r) {
      float4 xv = *reinterpret_cast<const float4*>(&sx[r][k]);
      aq[r] += xv.x * wq0 + xv.y * wq1 + xv.z * wq2 + xv.w * wq3;
      ak[r] += xv.x * wk0 + xv.y * wk1 + xv.z * wk2 + xv.w * wk3;
      av[r] += xv.x * wv0 + xv.y * wv1 + xv.z * wv2 + xv.w * wv3;
    }
  }

#pragma unroll
  for (int r = 0; r < 8; ++r) {
    const int row = rb + r;
    float q = aq[r] * 0.125f;                 // fold 1/sqrt(d_kq)
    ushort qh = bf16_of(q);
    Qh[row * DH + c] = qh;
    Ql[row * DH + c] = bf16_of(q - f_of_bf16(qh));
    float kk = ak[r];
    ushort kh = bf16_of(kk);
    Kh[row * DH + c] = kh;
    Kl[row * DH + c] = bf16_of(kk - f_of_bf16(kh));
    Vt[(size_t)c * SEQ + row] = bf16_of(av[r]);   // transposed
  }
}

// ---------------------------------------------------------------------------
// Kernel 2: flash attention partials.  Grid = 256 Q-tiles x 4 seq-splits.
// Block = 128 threads (2 waves, 16 Q-rows each).  Per iter: stage 64-row
// K-hi/K-lo/V^T tiles into padded LDS; S-tile = 3-pass split-bf16 MFMA;
// online softmax in fp32; P via LDS round-trip; PV in bf16 MFMA.
// MFMA layouts (measured, learn_hip m89/m120): C/D col=lane&15,
// row=(lane>>4)*4+reg;  A: m=lane&15, k=(lane>>4)*8+j;  B: n=lane&15,
// k=(lane>>4)*8+j.
// ---------------------------------------------------------------------------
__global__ __launch_bounds__(128) void flash_kernel(
    const ushort* __restrict__ Qh, const ushort* __restrict__ Ql,
    const ushort* __restrict__ Kh, const ushort* __restrict__ Kl,
    const ushort* __restrict__ Vt,
    float* __restrict__ Opart, float* __restrict__ Mpart,
    float* __restrict__ Lpart) {
  __shared__ __attribute__((aligned(16))) ushort sKh[BK][LDP];
  __shared__ __attribute__((aligned(16))) ushort sKl[BK][LDP];
  __shared__ __attribute__((aligned(16))) ushort sVt[BK][LDP];  // [vcol][seq]
  __shared__ __attribute__((aligned(16))) ushort sP[2][16][LDP];

  const int tid  = threadIdx.x;
  const int wv   = tid >> 6;        // wave 0/1 -> Q-row group
  const int lane = tid & 63;
  const int ln   = lane & 15;
  const int qd   = lane >> 4;       // quad 0..3
  const int bid  = blockIdx.x;
  const int qt   = bid >> 2;        // Q-tile 0..255
  const int sg   = bid & 3;         // seq split 0..3
  const int qrow0  = qt * 32 + wv * 16;
  const int k0base = sg * CHUNK;

  // Q fragments (A-operand layout), loaded once from global
  short8 aqh[2], aql[2];
#pragma unroll
  for (int kt = 0; kt < 2; ++kt) {
    aqh[kt] = *reinterpret_cast<const short8*>(Qh + (size_t)(qrow0 + ln) * DH + kt * 32 + qd * 8);
    aql[kt] = *reinterpret_cast<const short8*>(Ql + (size_t)(qrow0 + ln) * DH + kt * 32 + qd * 8);
  }

  f32x4 accO[4];
  float m_r[4], l_r[4];
#pragma unroll
  for (int nt = 0; nt < 4; ++nt)
#pragma unroll
    for (int i = 0; i < 4; ++i) accO[nt][i] = 0.f;
#pragma unroll
  for (int r = 0; r < 4; ++r) { m_r[r] = -INFINITY; l_r[r] = 0.f; }

  for (int it = 0; it < NITER; ++it) {
    const int k0 = k0base + it * BK;
    __syncthreads();  // previous iter's LDS reads done before restage
    // stage K-hi, K-lo, V^T tiles: 512 uint4 chunks each / 128 threads
#pragma unroll
    for (int j = 0; j < 4; ++j) {
      const int cidx = tid + 128 * j;        // 0..511
      const int row  = cidx >> 3;            // 0..63
      const int cc   = (cidx & 7) * 8;       // 0..56
      *reinterpret_cast<uint4*>(&sKh[row][cc]) =
          *reinterpret_cast<const uint4*>(Kh + (size_t)(k0 + row) * DH + cc);
      *reinterpret_cast<uint4*>(&sKl[row][cc]) =
          *reinterpret_cast<const uint4*>(Kl + (size_t)(k0 + row) * DH + cc);
      *reinterpret_cast<uint4*>(&sVt[row][cc]) =
          *reinterpret_cast<const uint4*>(Vt + (size_t)row * SEQ + k0 + cc);
    }
    __syncthreads();

    // S tile (16x64): 3-pass split precision, fp32 accumulate
    f32x4 accS[4];
#pragma unroll
    for (int nt = 0; nt < 4; ++nt) {
#pragma unroll
      for (int i = 0; i < 4; ++i) accS[nt][i] = 0.f;
#pragma unroll
      for (int kt = 0; kt < 2; ++kt) {
        short8 bh = *reinterpret_cast<const short8*>(&sKh[nt * 16 + ln][kt * 32 + qd * 8]);
        short8 bl = *reinterpret_cast<const short8*>(&sKl[nt * 16 + ln][kt * 32 + qd * 8]);
        accS[nt] = mfma16(aqh[kt], bh, accS[nt]);  // hi*hi
        accS[nt] = mfma16(aqh[kt], bl, accS[nt]);  // hi*lo
        accS[nt] = mfma16(aql[kt], bh, accS[nt]);  // lo*hi
      }
    }

    // online softmax (per reg r -> row qd*4+r; row data spans 16 lanes x 4 nt)
#pragma unroll
    for (int r = 0; r < 4; ++r) {
      float mx = fmaxf(fmaxf(accS[0][r], accS[1][r]), fmaxf(accS[2][r], accS[3][r]));
      mx = fmaxf(mx, __shfl_xor(mx, 1));
      mx = fmaxf(mx, __shfl_xor(mx, 2));
      mx = fmaxf(mx, __shfl_xor(mx, 4));
      mx = fmaxf(mx, __shfl_xor(mx, 8));
      const float mnew  = fmaxf(m_r[r], mx);
      const float alpha = __expf(m_r[r] - mnew);
      float ps = 0.f;
#pragma unroll
      for (int nt = 0; nt < 4; ++nt) {
        float p = __expf(accS[nt][r] - mnew);
        sP[wv][qd * 4 + r][nt * 16 + ln] = bf16_of(p);
        ps += p;
      }
      ps += __shfl_xor(ps, 1);
      ps += __shfl_xor(ps, 2);
      ps += __shfl_xor(ps, 4);
      ps += __shfl_xor(ps, 8);
      l_r[r] = l_r[r] * alpha + ps;
      m_r[r] = mnew;
#pragma unroll
      for (int nt = 0; nt < 4; ++nt) accO[nt][r] *= alpha;
    }
    __syncthreads();  // P writes visible across lanes before A-frag reads

    // O += P @ V   (P from LDS in A-layout, V^T rows contiguous as B-frags)
#pragma unroll
    for (int kt = 0; kt < 2; ++kt) {
      short8 ap = *reinterpret_cast<const short8*>(&sP[wv][ln][kt * 32 + qd * 8]);
#pragma unroll
      for (int nt = 0; nt < 4; ++nt) {
        short8 bv = *reinterpret_cast<const short8*>(&sVt[nt * 16 + ln][kt * 32 + qd * 8]);
        accO[nt] = mfma16(ap, bv, accO[nt]);
      }
    }
  }

  // write partials (un-normalized O, running m and l)
  float* Ob = Opart + (size_t)bid * 32 * DH;
#pragma unroll
  for (int nt = 0; nt < 4; ++nt)
#pragma unroll
    for (int r = 0; r < 4; ++r)
      Ob[(wv * 16 + qd * 4 + r) * DH + nt * 16 + ln] = accO[nt][r];
  if (ln == 0) {
#pragma unroll
    for (int r = 0; r < 4; ++r) {
      Mpart[(size_t)bid * 32 + wv * 16 + qd * 4 + r] = m_r[r];
      Lpart[(size_t)bid * 32 + wv * 16 + qd * 4 + r] = l_r[r];
    }
  }
}

// ---------------------------------------------------------------------------
// Kernel 3: log-sum-exp merge of the 4 seq-split partials + final normalize.
// ---------------------------------------------------------------------------
__global__ __launch_bounds__(256) void merge_kernel(
    const float* __restrict__ Opart, const float* __restrict__ Mpart,
    const float* __restrict__ Lpart, float* __restrict__ out) {
  const int idx = blockIdx.x * 256 + threadIdx.x;   // 0 .. SEQ*DH
  const int row = idx >> 6;
  const int col = idx & 63;
  const int qt  = row >> 5;
  const int rr  = row & 31;

  float m[SG];
  float M = -INFINITY;
#pragma unroll
  for (int i = 0; i < SG; ++i) {
    m[i] = Mpart[(size_t)(qt * SG + i) * 32 + rr];
    M = fmaxf(M, m[i]);
  }
  float L = 0.f, acc = 0.f;
#pragma unroll
  for (int i = 0; i < SG; ++i) {
    const float w = __expf(m[i] - M);
    L   += w * Lpart[(size_t)(qt * SG + i) * 32 + rr];
    acc += w * Opart[(size_t)(qt * SG + i) * 32 * DH + rr * DH + col];
  }
  out[idx] = acc / L;
}

// ---------------------------------------------------------------------------
extern "C" void kernel_launch(void* const* d_in, const int* in_sizes, int n_in,
                              void* d_out, int out_size, void* d_ws, size_t ws_size,
                              hipStream_t stream) {
  const float* x  = (const float*)d_in[0];
  const float* Wq = (const float*)d_in[1];
  const float* Wk = (const float*)d_in[2];
  const float* Wv = (const float*)d_in[3];
  float* out = (float*)d_out;

  // workspace layout (~13.9 MB total)
  const size_t S64 = (size_t)SEQ * DH;        // 524288 elements
  ushort* Qh = (ushort*)d_ws;
  ushort* Ql = Qh + S64;
  ushort* Kh = Ql + S64;
  ushort* Kl = Kh + S64;
  ushort* Vt = Kl + S64;
  float*  Op = (float*)(Vt + S64);            // [1024][32][64]
  float*  Mp = Op + (size_t)1024 * 32 * DH;
  float*  Lp = Mp + (size_t)1024 * 32;

  proj_kernel<<<SEQ / 8, 64, 0, stream>>>(x, Wq, Wk, Wv, Qh, Ql, Kh, Kl, Vt);
  flash_kernel<<<256 * SG, 128, 0, stream>>>(Qh, Ql, Kh, Kl, Vt, Op, Mp, Lp);
  merge_kernel<<<(SEQ * DH) / 256, 256, 0, stream>>>(Op, Mp, Lp, out);
}

// Round 2
// 280.949 us; speedup vs baseline: 1.0932x; 1.0932x over previous
//
#include <hip/hip_runtime.h>
#include <hip/hip_bf16.h>
#include <math.h>

#define SEQ 8192
#define DIN 512
#define DH  64
#define SG  8                 // sequence splits (flash)
#define CHUNK (SEQ / SG)      // 1024 K-rows per block
#define BK  64                // K/V rows per iteration
#define NITER (CHUNK / BK)    // 16
#define LDP 72                // padded LDS row stride (bf16 elems): 2-way banking = free

typedef float f32x4 __attribute__((ext_vector_type(4)));
typedef short short8 __attribute__((ext_vector_type(8)));

static __device__ __forceinline__ ushort bf16_of(float v) {
  __hip_bfloat16 h = __float2bfloat16(v);
  return *reinterpret_cast<ushort*>(&h);
}
static __device__ __forceinline__ float f_of_bf16(ushort u) {
  __hip_bfloat16 h;
  *reinterpret_cast<ushort*>(&h) = u;
  return __bfloat162float(h);
}
static __device__ __forceinline__ f32x4 mfma16(short8 a, short8 b, f32x4 c) {
  return __builtin_amdgcn_mfma_f32_16x16x32_bf16(a, b, c, 0, 0, 0);
}

// ---------------------------------------------------------------------------
// Kernel 1: projections, exact fp32.  2 waves/block split the K(=512) dim
// (256 each) -> 2048 waves = 8 waves/CU for latency hiding; W registers are
// software-prefetched (ping-pong) so the L2 load latency overlaps the FMAs.
// Halves combined through LDS; wave 0 does the bf16 hi/lo split + stores.
// Q gets the 1/sqrt(64)=0.125 scale folded in.  V written transposed (packed
// 16B store per lane).
// ---------------------------------------------------------------------------
__global__ __launch_bounds__(128, 2) void proj_kernel(
    const float* __restrict__ x,  const float* __restrict__ Wq,
    const float* __restrict__ Wk, const float* __restrict__ Wv,
    ushort* __restrict__ Qh, ushort* __restrict__ Ql,
    ushort* __restrict__ Kh, ushort* __restrict__ Kl,
    ushort* __restrict__ Vt) {
  __shared__ float sx[8][DIN];          // 16 KB; reused as combine buffer
  const int tid = threadIdx.x;          // 0..127
  const int rb  = blockIdx.x * 8;

  // stage 8 rows of x: 1024 float4 / 128 threads = 8 each, coalesced
  {
    const float4* xg  = reinterpret_cast<const float4*>(x + (size_t)rb * DIN);
    float4*       sxv = reinterpret_cast<float4*>(&sx[0][0]);
#pragma unroll
    for (int j = 0; j < 8; ++j) sxv[tid + 128 * j] = xg[tid + 128 * j];
  }
  __syncthreads();

  const int c  = tid & 63;   // output column
  const int w  = tid >> 6;   // k-half: wave 0 -> k in [0,256), wave 1 -> [256,512)
  const int kb = w * 256;

  float aq[8], ak[8], av[8];
#pragma unroll
  for (int r = 0; r < 8; ++r) { aq[r] = 0.f; ak[r] = 0.f; av[r] = 0.f; }

  float wc[12], wn[12];
#define LDW(dst, kk)                                                        \
  do {                                                                      \
    dst[0]  = Wq[(kk) * DH + c];  dst[1]  = Wq[((kk) + 1) * DH + c];        \
    dst[2]  = Wq[((kk) + 2) * DH + c]; dst[3] = Wq[((kk) + 3) * DH + c];    \
    dst[4]  = Wk[(kk) * DH + c];  dst[5]  = Wk[((kk) + 1) * DH + c];        \
    dst[6]  = Wk[((kk) + 2) * DH + c]; dst[7] = Wk[((kk) + 3) * DH + c];    \
    dst[8]  = Wv[(kk) * DH + c];  dst[9]  = Wv[((kk) + 1) * DH + c];        \
    dst[10] = Wv[((kk) + 2) * DH + c]; dst[11] = Wv[((kk) + 3) * DH + c];   \
  } while (0)
#define FMA4(wreg, k_)                                                      \
  do {                                                                      \
    _Pragma("unroll") for (int r = 0; r < 8; ++r) {                         \
      float4 xv = *reinterpret_cast<const float4*>(&sx[r][(k_)]);           \
      aq[r] += xv.x * wreg[0] + xv.y * wreg[1] + xv.z * wreg[2] + xv.w * wreg[3];   \
      ak[r] += xv.x * wreg[4] + xv.y * wreg[5] + xv.z * wreg[6] + xv.w * wreg[7];   \
      av[r] += xv.x * wreg[8] + xv.y * wreg[9] + xv.z * wreg[10] + xv.w * wreg[11]; \
    }                                                                       \
  } while (0)

  LDW(wc, kb);
  for (int k = kb; k < kb + 256; k += 8) {
    LDW(wn, k + 4);          // prefetch next 4-k group while computing current
    FMA4(wc, k);
    const int k2 = (k + 8 < kb + 256) ? k + 8 : kb;  // dummy wrap on last iter
    LDW(wc, k2);
    FMA4(wn, k + 4);
  }
#undef LDW
#undef FMA4

  // combine the two k-halves through LDS (reuse sx storage)
  __syncthreads();  // x reads done before overwrite
  float* cb = &sx[0][0];  // 24 * 64 floats = 6 KB
  if (w == 1) {
#pragma unroll
    for (int r = 0; r < 8; ++r) {
      cb[r * 64 + c]        = aq[r];
      cb[(8 + r) * 64 + c]  = ak[r];
      cb[(16 + r) * 64 + c] = av[r];
    }
  }
  __syncthreads();
  if (w == 0) {
    ushort vpack[8];
#pragma unroll
    for (int r = 0; r < 8; ++r) {
      const int row = rb + r;
      float q = (aq[r] + cb[r * 64 + c]) * 0.125f;   // fold 1/sqrt(d_kq)
      ushort qh = bf16_of(q);
      Qh[row * DH + c] = qh;
      Ql[row * DH + c] = bf16_of(q - f_of_bf16(qh));
      float kk = ak[r] + cb[(8 + r) * 64 + c];
      ushort kh = bf16_of(kk);
      Kh[row * DH + c] = kh;
      Kl[row * DH + c] = bf16_of(kk - f_of_bf16(kh));
      vpack[r] = bf16_of(av[r] + cb[(16 + r) * 64 + c]);
    }
    *reinterpret_cast<short8*>(Vt + (size_t)c * SEQ + rb) =
        *reinterpret_cast<short8*>(vpack);           // transposed, 16B packed
  }
}

// ---------------------------------------------------------------------------
// Kernel 2: flash attention partials — BARRIER-FREE K-loop.
// K/V (3 MB total) is L2-resident on every XCD, so MFMA B-fragments are read
// straight from global (no LDS staging, no __syncthreads).  LDS is used only
// for the per-wave P transpose (C-layout -> A-layout), which is a same-wave
// dependency the compiler handles with lgkmcnt waits.
// Grid = 128 Q-tiles(64 rows) x 8 seq-splits; block = 256 thr = 4 waves,
// 16 Q-rows per wave.  16 waves/CU.
// MFMA layouts (measured, m89/m120): C/D col=lane&15, row=(lane>>4)*4+reg;
// A: m=lane&15, k=(lane>>4)*8+j;  B: n=lane&15, k=(lane>>4)*8+j.
// ---------------------------------------------------------------------------
__global__ __launch_bounds__(256, 4) void flash_kernel(
    const ushort* __restrict__ Qh, const ushort* __restrict__ Ql,
    const ushort* __restrict__ Kh, const ushort* __restrict__ Kl,
    const ushort* __restrict__ Vt,
    ushort* __restrict__ Opart, float* __restrict__ Mpart,
    float* __restrict__ Lpart) {
  __shared__ __attribute__((aligned(16))) ushort sP[4][16][LDP];  // 9.2 KB

  const int tid  = threadIdx.x;
  const int wv   = tid >> 6;        // wave 0..3 -> Q-row group
  const int lane = tid & 63;
  const int ln   = lane & 15;
  const int qd   = lane >> 4;       // quad 0..3
  const int bid  = blockIdx.x;
  const int qt   = bid >> 3;        // Q-tile 0..127
  const int sg   = bid & 7;         // seq split 0..7
  const int qrow0  = qt * 64 + wv * 16;
  const int k0base = sg * CHUNK;

  // Q fragments (A-layout), loaded once
  short8 aqh[2], aql[2];
#pragma unroll
  for (int kt = 0; kt < 2; ++kt) {
    aqh[kt] = *reinterpret_cast<const short8*>(Qh + (size_t)(qrow0 + ln) * DH + kt * 32 + qd * 8);
    aql[kt] = *reinterpret_cast<const short8*>(Ql + (size_t)(qrow0 + ln) * DH + kt * 32 + qd * 8);
  }

  f32x4 accO[4];
  float m_r[4], l_r[4];
#pragma unroll
  for (int nt = 0; nt < 4; ++nt)
#pragma unroll
    for (int i = 0; i < 4; ++i) accO[nt][i] = 0.f;
#pragma unroll
  for (int r = 0; r < 4; ++r) { m_r[r] = -INFINITY; l_r[r] = 0.f; }

  for (int it = 0; it < NITER; ++it) {
    const int k0 = k0base + it * BK;

    // V B-fragments (held through softmax)
    short8 bv[4][2];
#pragma unroll
    for (int nt = 0; nt < 4; ++nt)
#pragma unroll
      for (int kt = 0; kt < 2; ++kt)
        bv[nt][kt] = *reinterpret_cast<const short8*>(
            Vt + (size_t)(nt * 16 + ln) * SEQ + k0 + kt * 32 + qd * 8);

    // S tile (16x64): 3-pass split-precision MFMA, B-frags straight from L2
    f32x4 accS[4];
#pragma unroll
    for (int nt = 0; nt < 4; ++nt) {
#pragma unroll
      for (int i = 0; i < 4; ++i) accS[nt][i] = 0.f;
#pragma unroll
      for (int kt = 0; kt < 2; ++kt) {
        short8 bh = *reinterpret_cast<const short8*>(
            Kh + (size_t)(k0 + nt * 16 + ln) * DH + kt * 32 + qd * 8);
        short8 bl = *reinterpret_cast<const short8*>(
            Kl + (size_t)(k0 + nt * 16 + ln) * DH + kt * 32 + qd * 8);
        accS[nt] = mfma16(aqh[kt], bh, accS[nt]);  // hi*hi
        accS[nt] = mfma16(aqh[kt], bl, accS[nt]);  // hi*lo
        accS[nt] = mfma16(aql[kt], bh, accS[nt]);  // lo*hi
      }
    }

    // online softmax (row qd*4+r lives in the 16-lane group of this quad)
#pragma unroll
    for (int r = 0; r < 4; ++r) {
      float mx = fmaxf(fmaxf(accS[0][r], accS[1][r]), fmaxf(accS[2][r], accS[3][r]));
      mx = fmaxf(mx, __shfl_xor(mx, 1));
      mx = fmaxf(mx, __shfl_xor(mx, 2));
      mx = fmaxf(mx, __shfl_xor(mx, 4));
      mx = fmaxf(mx, __shfl_xor(mx, 8));
      const float mnew  = fmaxf(m_r[r], mx);
      const float alpha = __expf(m_r[r] - mnew);
      float ps = 0.f;
#pragma unroll
      for (int nt = 0; nt < 4; ++nt) {
        float p = __expf(accS[nt][r] - mnew);
        sP[wv][qd * 4 + r][nt * 16 + ln] = bf16_of(p);
        ps += p;
      }
      ps += __shfl_xor(ps, 1);
      ps += __shfl_xor(ps, 2);
      ps += __shfl_xor(ps, 4);
      ps += __shfl_xor(ps, 8);
      l_r[r] = l_r[r] * alpha + ps;
      m_r[r] = mnew;
#pragma unroll
      for (int nt = 0; nt < 4; ++nt) accO[nt][r] *= alpha;
    }
    // no barrier: sP[wv] is private to this wave; same-wave LDS deps only

    // O += P @ V
#pragma unroll
    for (int kt = 0; kt < 2; ++kt) {
      short8 ap = *reinterpret_cast<const short8*>(&sP[wv][ln][kt * 32 + qd * 8]);
#pragma unroll
      for (int nt = 0; nt < 4; ++nt)
        accO[nt] = mfma16(ap, bv[nt][kt], accO[nt]);
    }
  }

  // partials: un-normalized O (bf16), running m and l (fp32)
  ushort* Ob = Opart + ((size_t)sg * SEQ + qrow0) * DH;
#pragma unroll
  for (int nt = 0; nt < 4; ++nt)
#pragma unroll
    for (int r = 0; r < 4; ++r)
      Ob[(qd * 4 + r) * DH + nt * 16 + ln] = bf16_of(accO[nt][r]);
  if (ln == 0) {
#pragma unroll
    for (int r = 0; r < 4; ++r) {
      Mpart[(size_t)sg * SEQ + qrow0 + qd * 4 + r] = m_r[r];
      Lpart[(size_t)sg * SEQ + qrow0 + qd * 4 + r] = l_r[r];
    }
  }
}

// ---------------------------------------------------------------------------
// Kernel 3: log-sum-exp merge of the 8 seq-split partials + normalize.
// ---------------------------------------------------------------------------
__global__ __launch_bounds__(256) void merge_kernel(
    const ushort* __restrict__ Opart, const float* __restrict__ Mpart,
    const float* __restrict__ Lpart, float* __restrict__ out) {
  const int idx = blockIdx.x * 256 + threadIdx.x;   // 0 .. SEQ*DH
  const int row = idx >> 6;
  const int col = idx & 63;

  float m[SG];
  float M = -INFINITY;
#pragma unroll
  for (int i = 0; i < SG; ++i) {
    m[i] = Mpart[(size_t)i * SEQ + row];
    M = fmaxf(M, m[i]);
  }
  float L = 0.f, acc = 0.f;
#pragma unroll
  for (int i = 0; i < SG; ++i) {
    const float w = __expf(m[i] - M);
    L   += w * Lpart[(size_t)i * SEQ + row];
    acc += w * f_of_bf16(Opart[((size_t)i * SEQ + row) * DH + col]);
  }
  out[idx] = acc / L;
}

// ---------------------------------------------------------------------------
extern "C" void kernel_launch(void* const* d_in, const int* in_sizes, int n_in,
                              void* d_out, int out_size, void* d_ws, size_t ws_size,
                              hipStream_t stream) {
  const float* x  = (const float*)d_in[0];
  const float* Wq = (const float*)d_in[1];
  const float* Wk = (const float*)d_in[2];
  const float* Wv = (const float*)d_in[3];
  float* out = (float*)d_out;

  // workspace layout (~13.8 MB, matches round-1-proven footprint)
  const size_t S64 = (size_t)SEQ * DH;        // 524288
  ushort* Qh = (ushort*)d_ws;
  ushort* Ql = Qh + S64;
  ushort* Kh = Ql + S64;
  ushort* Kl = Kh + S64;
  ushort* Vt = Kl + S64;
  ushort* Op = Vt + S64;                      // [SG][SEQ][DH] bf16
  float*  Mp = (float*)(Op + (size_t)SG * S64);
  float*  Lp = Mp + (size_t)SG * SEQ;

  proj_kernel<<<SEQ / 8, 128, 0, stream>>>(x, Wq, Wk, Wv, Qh, Ql, Kh, Kl, Vt);
  flash_kernel<<<(SEQ / 64) * SG, 256, 0, stream>>>(Qh, Ql, Kh, Kl, Vt, Op, Mp, Lp);
  merge_kernel<<<(SEQ * DH) / 256, 256, 0, stream>>>(Op, Mp, Lp, out);
}